// Round 2
// baseline (801.071 us; speedup 1.0000x reference)
//
#include <hip/hip_runtime.h>

typedef unsigned short u16;
typedef unsigned int u32;

#define Nn 100000
#define Ee 500000
#define DIM 160
#define CAP 48

__device__ __forceinline__ u16 f2bf(float f) {
    u32 i = __float_as_uint(f);
    return (u16)((i + 0x7FFFu + ((i >> 16) & 1u)) >> 16);
}

// ---------------- K1: histogram + bucket fill (one pass) ---------------------
__global__ __launch_bounds__(256) void hist_fill_k(const int* __restrict__ ei,
                                                   int* __restrict__ cnt,
                                                   int* __restrict__ bucket) {
    int e = blockIdx.x * 256 + threadIdx.x;
    if (e >= Ee) return;
    int dst = ei[Ee + e];                 // edge_index row 1 (dst)
    int pos = atomicAdd(&cnt[dst], 1);
    if (pos < CAP) bucket[(size_t)dst * CAP + pos] = e;
}

// ------- K2: fused gather + /sqrt5 + feats + bf16-pack + transpose -----------
// Block = 512 threads (8 waves) handles 64 nodes; wave per node (8 seq each).
// Packs (msg bf16 << 16 | feat bf16) per element; LDS tile then coalesced
// u32 row writes into mfT [160][N].
__global__ __launch_bounds__(512) void gather_tr_k(const float* __restrict__ em,
                                                   const float* __restrict__ feats,
                                                   const int* __restrict__ bucket,
                                                   const int* __restrict__ cnt,
                                                   u32* __restrict__ mfT) {
    __shared__ u32 tile[160][66];         // col stride 66: 2-way (free) on writes
    int n0 = blockIdx.x * 64;
    int w = threadIdx.x >> 6;             // wave id 0..7
    int lane = threadIdx.x & 63;
    const float s = 0.4472135954999579f;  // 1/sqrt(5)

    for (int i = 0; i < 8; ++i) {
        int col = w * 8 + i;
        int n = n0 + col;
        float a0 = 0.f, a1 = 0.f, a2 = 0.f;
        float f0 = 0.f, f1 = 0.f, f2 = 0.f;
        if (n < Nn) {
            int deg = cnt[n];
            if (deg > CAP) deg = CAP;
            const int* base = bucket + (size_t)n * CAP;
            for (int k = 0; k < deg; ++k) {
                int e = base[k];                     // wave-uniform broadcast
                const float* r = em + (size_t)e * DIM;
                a0 += r[lane];
                a1 += r[64 + lane];
                if (lane < 32) a2 += r[128 + lane];
            }
            const float* f = feats + (size_t)n * DIM;
            f0 = f[lane];
            f1 = f[64 + lane];
            if (lane < 32) f2 = f[128 + lane];
        }
        tile[lane][col]      = ((u32)f2bf(a0 * s) << 16) | f2bf(f0);
        tile[64 + lane][col] = ((u32)f2bf(a1 * s) << 16) | f2bf(f1);
        if (lane < 32)
            tile[128 + lane][col] = ((u32)f2bf(a2 * s) << 16) | f2bf(f2);
    }
    __syncthreads();
    int n = n0 + lane;
    if (n < Nn) {
        for (int k = 0; k < 20; ++k) {        // 160 rows / 8 waves
            int d = w * 20 + k;
            mfT[d * Nn + n] = tile[d][lane];  // 256B contiguous per wave
        }
    }
}

// ---------------- K4: pre-scale + fuse all weight factors (f32) --------------
// Layout in W (f32): Wls' [96][96] @0, Wlv' [96][32] @9216, W000' [64][96] @12288,
//                    W110' [32][96] @18432, W011' [64][32] @21504, W101' [32][32] @23552
__global__ __launch_bounds__(256) void prep_weights_k(
    const float* __restrict__ Wls, const float* __restrict__ Wlv,
    const float* __restrict__ W000, const float* __restrict__ W110,
    const float* __restrict__ W011, const float* __restrict__ W101,
    const float* __restrict__ w00, const float* __restrict__ w01,
    const float* __restrict__ w10, const float* __restrict__ w11,
    float* __restrict__ W) {
    int i = blockIdx.x * 256 + threadIdx.x;
    const float inv_fan = 0.10206207261596577f;  // 1/sqrt(96)
    const float IS3 = 0.5773502691896258f;
    if (i < 9216) {
        int u = i / 96;
        float sc = inv_fan * (u < 64 ? w00[u] : IS3 * w11[u - 64]);
        W[i] = Wls[i] * sc;
    } else if (i < 12288) {
        int j = i - 9216; int u = j / 32;
        float sc = inv_fan * (u < 64 ? w01[u] : w10[u - 64]);
        W[i] = Wlv[j] * sc;
    } else if (i < 18432) {
        W[i] = W000[i - 12288] * 0.08838834764831845f;   // inv2/sqrt(64)
    } else if (i < 21504) {
        W[i] = W110[i - 18432] * (0.125f * IS3);         // inv2/sqrt(32) * IS3
    } else if (i < 23552) {
        W[i] = W011[i - 21504] * 0.08838834764831845f;   // inv2/sqrt(64)
    } else {
        W[i] = W101[i - 23552] * 0.125f;                 // inv2/sqrt(32)
    }
}

__device__ __forceinline__ float hi_f(u32 v) { return __uint_as_float(v & 0xFFFF0000u); }  // msg
__device__ __forceinline__ float lo_f(u32 v) { return __uint_as_float(v << 16); }          // feat

// ---------------- K5: h_s — one thread per (node, wb) ------------------------
// grid (391, 3): wb = blockIdx.y selects 32-wide w-block of the 96 h_s cols.
// wb 0,1 -> silu -> out[:, 0:64]; wb 2 -> sigmoid gates -> gbuf [32][N].
__global__ __launch_bounds__(256) void node_s_k(
    const u32* __restrict__ mfT, const float* __restrict__ attrs,
    const float* __restrict__ W, float* __restrict__ out,
    float* __restrict__ gbuf) {
    __shared__ float st[256][33];
    int wb = blockIdx.y;
    int n0 = blockIdx.x * 256;
    int t = threadIdx.x;
    int n = n0 + t;
    bool active = (n < Nn);
    int nc = active ? n : (Nn - 1);

    const float* Wls  = W;
    const float* W000 = W + 12288;
    const float* W110 = W + 18432;

    float4 a = *reinterpret_cast<const float4*>(attrs + (size_t)nc * 4);
    float a_s = a.x, av0 = a.y, av1 = a.z, av2 = a.w;

    float accU[32], accJ[32];
    #pragma unroll
    for (int w = 0; w < 32; ++w) { accU[w] = 0.f; accJ[w] = 0.f; }

    const float* R1 = Wls + wb * 32;     // row stride 96
    const float* R2 = W000 + wb * 32;
    const float* R3 = W110 + wb * 32;

    // s-part: both terms scale by a_s -> factored out of the loop
    for (int u = 0; u < 64; ++u) {
        u32 v = mfT[u * Nn + nc];
        float m = hi_f(v);
        float x = lo_f(v);
        const float* r1 = R1 + u * 96;
        const float* r2 = R2 + u * 96;
        #pragma unroll
        for (int w = 0; w < 32; ++w) accU[w] += m * r1[w] + x * r2[w];
    }
    // v-dot part (not scaled by a_s)
    for (int j = 0; j < 32; ++j) {
        int d = (64 + 3 * j) * Nn + nc;
        u32 v0 = mfT[d], v1 = mfT[d + Nn], v2 = mfT[d + 2 * Nn];
        float dv = hi_f(v0) * av0 + hi_f(v1) * av1 + hi_f(v2) * av2;
        float dx = lo_f(v0) * av0 + lo_f(v1) * av1 + lo_f(v2) * av2;
        const float* r1 = R1 + (64 + j) * 96;
        const float* r2 = R3 + j * 96;
        #pragma unroll
        for (int w = 0; w < 32; ++w) accJ[w] += dv * r1[w] + dx * r2[w];
    }

    if (wb < 2) {
        #pragma unroll
        for (int w = 0; w < 32; ++w) {
            float h = a_s * accU[w] + accJ[w];
            st[t][w] = h / (1.f + __expf(-h));   // silu
        }
        __syncthreads();
        // coalesced write: 8192 floats, lane-contiguous, full 64B lines
        int off = wb * 32;
        for (int k = 0; k < 32; ++k) {
            int f = k * 256 + t;
            int node = f >> 5, w = f & 31;
            int n2 = n0 + node;
            if (n2 < Nn) out[(size_t)n2 * DIM + off + w] = st[node][w];
        }
    } else {
        #pragma unroll
        for (int w = 0; w < 32; ++w) {
            float h = a_s * accU[w] + accJ[w];
            if (active) gbuf[w * Nn + n] = 1.f / (1.f + __expf(-h));
        }
    }
}

// ---------------- K6: h_v — one thread per (node, half) ----------------------
// grid (391, 2): half = blockIdx.y selects 16 of the 32 v-channels; all 3
// components per thread so each node's 48 output floats are contiguous.
__global__ __launch_bounds__(256) void node_v_k(
    const u32* __restrict__ mfT, const float* __restrict__ attrs,
    const float* __restrict__ W, const float* __restrict__ gbuf,
    float* __restrict__ out) {
    __shared__ float st[256][49];
    int half = blockIdx.y;
    int w0 = half * 16;
    int n0 = blockIdx.x * 256;
    int t = threadIdx.x;
    int n = n0 + t;
    bool active = (n < Nn);
    int nc = active ? n : (Nn - 1);

    const float* Wlv  = W + 9216;   // [96][32]
    const float* W011 = W + 21504;  // [64][32]
    const float* W101 = W + 23552;  // [32][32]

    float4 a = *reinterpret_cast<const float4*>(attrs + (size_t)nc * 4);
    float a_s = a.x;
    float av[3] = {a.y, a.z, a.w};

    // ss[w] = sum_u ms[u]*Wlv'[u][w] + xs[u]*W011'[u][w]
    float ss[16];
    #pragma unroll
    for (int w = 0; w < 16; ++w) ss[w] = 0.f;
    for (int u = 0; u < 64; ++u) {
        u32 v = mfT[u * Nn + nc];
        float m = hi_f(v);
        float x = lo_f(v);
        const float* r1 = Wlv + u * 32 + w0;
        const float* r2 = W011 + u * 32 + w0;
        #pragma unroll
        for (int w = 0; w < 16; ++w) ss[w] += m * r1[w] + x * r2[w];
    }

    // hj[w][c] = sum_j mv[j][c]*Wlv'[64+j][w] + xv[j][c]*W101'[j][w]  (x a_s later)
    float hj[16][3];
    #pragma unroll
    for (int w = 0; w < 16; ++w) {
        hj[w][0] = 0.f; hj[w][1] = 0.f; hj[w][2] = 0.f;
    }
    for (int j = 0; j < 32; ++j) {
        int d = (64 + 3 * j) * Nn + nc;
        u32 v0 = mfT[d], v1 = mfT[d + Nn], v2 = mfT[d + 2 * Nn];
        float m0 = hi_f(v0), m1 = hi_f(v1), m2 = hi_f(v2);
        float x0 = lo_f(v0), x1 = lo_f(v1), x2 = lo_f(v2);
        const float* r1 = Wlv + (64 + j) * 32 + w0;
        const float* r2 = W101 + j * 32 + w0;
        #pragma unroll
        for (int w = 0; w < 16; ++w) {
            float wv = r1[w], wx = r2[w];
            hj[w][0] += m0 * wv + x0 * wx;
            hj[w][1] += m1 * wv + x1 * wx;
            hj[w][2] += m2 * wv + x2 * wx;
        }
    }

    #pragma unroll
    for (int w = 0; w < 16; ++w) {
        float g = gbuf[(w0 + w) * Nn + nc];
        #pragma unroll
        for (int c = 0; c < 3; ++c) {
            float hv = av[c] * ss[w] + a_s * hj[w][c];
            st[t][w * 3 + c] = g * hv;
        }
    }
    __syncthreads();
    // coalesced write: each node's 48 floats are contiguous (192B = 3 lines)
    int off = 64 + w0 * 3;
    for (int k = 0; k < 48; ++k) {
        int f = k * 256 + t;
        int node = f / 48;
        int idx = f - node * 48;
        int n2 = n0 + node;
        if (n2 < Nn) out[(size_t)n2 * DIM + off + idx] = st[node][idx];
    }
}

extern "C" void kernel_launch(void* const* d_in, const int* in_sizes, int n_in,
                              void* d_out, int out_size, void* d_ws, size_t ws_size,
                              hipStream_t stream) {
    const float* feats = (const float*)d_in[0];
    const float* attrs = (const float*)d_in[1];
    const float* em    = (const float*)d_in[2];
    const int*   ei    = (const int*)d_in[3];
    const float* w00   = (const float*)d_in[4];
    const float* w01   = (const float*)d_in[5];
    const float* w10   = (const float*)d_in[6];
    const float* w11   = (const float*)d_in[7];
    const float* Wls   = (const float*)d_in[8];
    const float* Wlv   = (const float*)d_in[9];
    const float* W000  = (const float*)d_in[10];
    const float* W110  = (const float*)d_in[11];
    const float* W011  = (const float*)d_in[12];
    const float* W101  = (const float*)d_in[13];

    char* ws = (char*)d_ws;
    int*   bucket = (int*)  (ws);                  // 19,200,000 B [N][48] int
    int*   cnt    = (int*)  (ws + 19200000);       //    400,000 B [N] int
    u32*   mfT    = (u32*)  (ws + 19600000);       // 64,000,000 B [160][N] u32 (msg|feat bf16)
    float* gbuf   = (float*)(ws + 83600000);       // 12,800,000 B [32][N] f32 gates
    float* W      = (float*)(ws + 96400000);       //     98,304 B weights

    hipMemsetAsync(cnt, 0, Nn * sizeof(int), stream);

    hist_fill_k<<<(Ee + 255) / 256, 256, 0, stream>>>(ei, cnt, bucket);

    gather_tr_k<<<(Nn + 63) / 64, 512, 0, stream>>>(em, feats, bucket, cnt, mfT);

    prep_weights_k<<<96, 256, 0, stream>>>(Wls, Wlv, W000, W110, W011, W101,
                                           w00, w01, w10, w11, W);

    node_s_k<<<dim3((Nn + 255) / 256, 3), 256, 0, stream>>>(mfT, attrs, W,
                                                            (float*)d_out, gbuf);

    node_v_k<<<dim3((Nn + 255) / 256, 2), 256, 0, stream>>>(mfT, attrs, W,
                                                            gbuf, (float*)d_out);
}

// Round 3
// 743.753 us; speedup vs baseline: 1.0771x; 1.0771x over previous
//
#include <hip/hip_runtime.h>

typedef unsigned short u16;
typedef unsigned int u32;

#define Nn 100000
#define Ee 500000
#define DIM 160
#define CAP 48

__device__ __forceinline__ u16 f2bf(float f) {
    u32 i = __float_as_uint(f);
    return (u16)((i + 0x7FFFu + ((i >> 16) & 1u)) >> 16);
}

// ---------------- K1: histogram + bucket fill (one pass) ---------------------
__global__ __launch_bounds__(256) void hist_fill_k(const int* __restrict__ ei,
                                                   int* __restrict__ cnt,
                                                   int* __restrict__ bucket) {
    int e = blockIdx.x * 256 + threadIdx.x;
    if (e >= Ee) return;
    int dst = ei[Ee + e];                 // edge_index row 1 (dst)
    int pos = atomicAdd(&cnt[dst], 1);
    if (pos < CAP) bucket[(size_t)dst * CAP + pos] = e;
}

// ------- K2: fused gather + /sqrt5 + feats + bf16-pack + transpose -----------
// Block = 512 threads (8 waves) handles 64 nodes; wave per node (8 seq each).
// int4-batched edge-id loads + 4-edge unroll => ~12 independent row loads in
// flight per round instead of a serialized chain per edge (latency fix).
__global__ __launch_bounds__(512) void gather_tr_k(const float* __restrict__ em,
                                                   const float* __restrict__ feats,
                                                   const int* __restrict__ bucket,
                                                   const int* __restrict__ cnt,
                                                   u32* __restrict__ mfT) {
    __shared__ u32 tile[160][65];         // stride 65 % 32 == 1: conflict-free
    int n0 = blockIdx.x * 64;
    int w = threadIdx.x >> 6;             // wave id 0..7
    int lane = threadIdx.x & 63;
    const float s = 0.4472135954999579f;  // 1/sqrt(5)

    for (int i = 0; i < 8; ++i) {
        int col = w * 8 + i;
        int n = n0 + col;
        float a0 = 0.f, a1 = 0.f, a2 = 0.f;
        float f0 = 0.f, f1 = 0.f, f2 = 0.f;
        if (n < Nn) {
            const float* f = feats + (size_t)n * DIM;
            f0 = f[lane];
            f1 = f[64 + lane];
            if (lane < 32) f2 = f[128 + lane];

            int deg = cnt[n];
            if (deg > CAP) deg = CAP;
            const int* base = bucket + (size_t)n * CAP;   // 192B-aligned row
            int k = 0;
            for (; k + 4 <= deg; k += 4) {
                int4 ee = *reinterpret_cast<const int4*>(base + k);  // 16B, aligned
                const float* p0 = em + (size_t)ee.x * DIM;
                const float* p1 = em + (size_t)ee.y * DIM;
                const float* p2 = em + (size_t)ee.z * DIM;
                const float* p3 = em + (size_t)ee.w * DIM;
                float t00 = p0[lane], t10 = p1[lane], t20 = p2[lane], t30 = p3[lane];
                float t01 = p0[64 + lane], t11 = p1[64 + lane];
                float t21 = p2[64 + lane], t31 = p3[64 + lane];
                a0 += (t00 + t10) + (t20 + t30);
                a1 += (t01 + t11) + (t21 + t31);
                if (lane < 32)
                    a2 += (p0[128 + lane] + p1[128 + lane])
                        + (p2[128 + lane] + p3[128 + lane]);
            }
            if (k + 2 <= deg) {           // k is a multiple of 4 -> 8B aligned
                int2 ee = *reinterpret_cast<const int2*>(base + k);
                const float* p0 = em + (size_t)ee.x * DIM;
                const float* p1 = em + (size_t)ee.y * DIM;
                a0 += p0[lane] + p1[lane];
                a1 += p0[64 + lane] + p1[64 + lane];
                if (lane < 32) a2 += p0[128 + lane] + p1[128 + lane];
                k += 2;
            }
            if (k < deg) {
                int e = base[k];
                const float* r = em + (size_t)e * DIM;
                a0 += r[lane];
                a1 += r[64 + lane];
                if (lane < 32) a2 += r[128 + lane];
            }
        }
        tile[lane][col]      = ((u32)f2bf(a0 * s) << 16) | f2bf(f0);
        tile[64 + lane][col] = ((u32)f2bf(a1 * s) << 16) | f2bf(f1);
        if (lane < 32)
            tile[128 + lane][col] = ((u32)f2bf(a2 * s) << 16) | f2bf(f2);
    }
    __syncthreads();
    int n = n0 + lane;
    if (n < Nn) {
        for (int k = 0; k < 20; ++k) {        // 160 rows / 8 waves
            int d = w * 20 + k;
            mfT[d * Nn + n] = tile[d][lane];  // 256B contiguous per wave
        }
    }
}

// ---------------- K4: pre-scale + fuse all weight factors (f32) --------------
// Layout in W (f32): Wls' [96][96] @0, Wlv' [96][32] @9216, W000' [64][96] @12288,
//                    W110' [32][96] @18432, W011' [64][32] @21504, W101' [32][32] @23552
__global__ __launch_bounds__(256) void prep_weights_k(
    const float* __restrict__ Wls, const float* __restrict__ Wlv,
    const float* __restrict__ W000, const float* __restrict__ W110,
    const float* __restrict__ W011, const float* __restrict__ W101,
    const float* __restrict__ w00, const float* __restrict__ w01,
    const float* __restrict__ w10, const float* __restrict__ w11,
    float* __restrict__ W) {
    int i = blockIdx.x * 256 + threadIdx.x;
    const float inv_fan = 0.10206207261596577f;  // 1/sqrt(96)
    const float IS3 = 0.5773502691896258f;
    if (i < 9216) {
        int u = i / 96;
        float sc = inv_fan * (u < 64 ? w00[u] : IS3 * w11[u - 64]);
        W[i] = Wls[i] * sc;
    } else if (i < 12288) {
        int j = i - 9216; int u = j / 32;
        float sc = inv_fan * (u < 64 ? w01[u] : w10[u - 64]);
        W[i] = Wlv[j] * sc;
    } else if (i < 18432) {
        W[i] = W000[i - 12288] * 0.08838834764831845f;   // inv2/sqrt(64)
    } else if (i < 21504) {
        W[i] = W110[i - 18432] * (0.125f * IS3);         // inv2/sqrt(32) * IS3
    } else if (i < 23552) {
        W[i] = W011[i - 21504] * 0.08838834764831845f;   // inv2/sqrt(64)
    } else {
        W[i] = W101[i - 23552] * 0.125f;                 // inv2/sqrt(32)
    }
}

__device__ __forceinline__ float hi_f(u32 v) { return __uint_as_float(v & 0xFFFF0000u); }  // msg
__device__ __forceinline__ float lo_f(u32 v) { return __uint_as_float(v << 16); }          // feat

// ---------------- K5: h_s — one thread per (node, wb) ------------------------
// grid (391, 3): wb = blockIdx.y selects 32-wide w-block of the 96 h_s cols.
// wb 0,1 -> silu -> out[:, 0:64]; wb 2 -> sigmoid gates -> gbuf [32][N].
__global__ __launch_bounds__(256) void node_s_k(
    const u32* __restrict__ mfT, const float* __restrict__ attrs,
    const float* __restrict__ W, float* __restrict__ out,
    float* __restrict__ gbuf) {
    __shared__ float st[256][33];
    int wb = blockIdx.y;
    int n0 = blockIdx.x * 256;
    int t = threadIdx.x;
    int n = n0 + t;
    bool active = (n < Nn);
    int nc = active ? n : (Nn - 1);

    const float* Wls  = W;
    const float* W000 = W + 12288;
    const float* W110 = W + 18432;

    float4 a = *reinterpret_cast<const float4*>(attrs + (size_t)nc * 4);
    float a_s = a.x, av0 = a.y, av1 = a.z, av2 = a.w;

    float accU[32], accJ[32];
    #pragma unroll
    for (int w = 0; w < 32; ++w) { accU[w] = 0.f; accJ[w] = 0.f; }

    const float* R1 = Wls + wb * 32;     // row stride 96
    const float* R2 = W000 + wb * 32;
    const float* R3 = W110 + wb * 32;

    // s-part: both terms scale by a_s -> factored out of the loop
    for (int u = 0; u < 64; ++u) {
        u32 v = mfT[u * Nn + nc];
        float m = hi_f(v);
        float x = lo_f(v);
        const float* r1 = R1 + u * 96;
        const float* r2 = R2 + u * 96;
        #pragma unroll
        for (int w = 0; w < 32; ++w) accU[w] += m * r1[w] + x * r2[w];
    }
    // v-dot part (not scaled by a_s)
    for (int j = 0; j < 32; ++j) {
        int d = (64 + 3 * j) * Nn + nc;
        u32 v0 = mfT[d], v1 = mfT[d + Nn], v2 = mfT[d + 2 * Nn];
        float dv = hi_f(v0) * av0 + hi_f(v1) * av1 + hi_f(v2) * av2;
        float dx = lo_f(v0) * av0 + lo_f(v1) * av1 + lo_f(v2) * av2;
        const float* r1 = R1 + (64 + j) * 96;
        const float* r2 = R3 + j * 96;
        #pragma unroll
        for (int w = 0; w < 32; ++w) accJ[w] += dv * r1[w] + dx * r2[w];
    }

    if (wb < 2) {
        #pragma unroll
        for (int w = 0; w < 32; ++w) {
            float h = a_s * accU[w] + accJ[w];
            st[t][w] = h / (1.f + __expf(-h));   // silu
        }
        __syncthreads();
        // coalesced write: 8192 floats, lane-contiguous, full 64B lines
        int off = wb * 32;
        for (int k = 0; k < 32; ++k) {
            int f = k * 256 + t;
            int node = f >> 5, w = f & 31;
            int n2 = n0 + node;
            if (n2 < Nn) out[(size_t)n2 * DIM + off + w] = st[node][w];
        }
    } else {
        #pragma unroll
        for (int w = 0; w < 32; ++w) {
            float h = a_s * accU[w] + accJ[w];
            if (active) gbuf[w * Nn + n] = 1.f / (1.f + __expf(-h));
        }
    }
}

// ---------------- K6: h_v — one thread per (node, half) ----------------------
// grid (391, 2): half = blockIdx.y selects 16 of the 32 v-channels; all 3
// components per thread so each node's 48 output floats are contiguous.
__global__ __launch_bounds__(256) void node_v_k(
    const u32* __restrict__ mfT, const float* __restrict__ attrs,
    const float* __restrict__ W, const float* __restrict__ gbuf,
    float* __restrict__ out) {
    __shared__ float st[256][49];
    int half = blockIdx.y;
    int w0 = half * 16;
    int n0 = blockIdx.x * 256;
    int t = threadIdx.x;
    int n = n0 + t;
    bool active = (n < Nn);
    int nc = active ? n : (Nn - 1);

    const float* Wlv  = W + 9216;   // [96][32]
    const float* W011 = W + 21504;  // [64][32]
    const float* W101 = W + 23552;  // [32][32]

    float4 a = *reinterpret_cast<const float4*>(attrs + (size_t)nc * 4);
    float a_s = a.x;
    float av[3] = {a.y, a.z, a.w};

    // ss[w] = sum_u ms[u]*Wlv'[u][w] + xs[u]*W011'[u][w]
    float ss[16];
    #pragma unroll
    for (int w = 0; w < 16; ++w) ss[w] = 0.f;
    for (int u = 0; u < 64; ++u) {
        u32 v = mfT[u * Nn + nc];
        float m = hi_f(v);
        float x = lo_f(v);
        const float* r1 = Wlv + u * 32 + w0;
        const float* r2 = W011 + u * 32 + w0;
        #pragma unroll
        for (int w = 0; w < 16; ++w) ss[w] += m * r1[w] + x * r2[w];
    }

    // hj[w][c] = sum_j mv[j][c]*Wlv'[64+j][w] + xv[j][c]*W101'[j][w]  (x a_s later)
    float hj[16][3];
    #pragma unroll
    for (int w = 0; w < 16; ++w) {
        hj[w][0] = 0.f; hj[w][1] = 0.f; hj[w][2] = 0.f;
    }
    for (int j = 0; j < 32; ++j) {
        int d = (64 + 3 * j) * Nn + nc;
        u32 v0 = mfT[d], v1 = mfT[d + Nn], v2 = mfT[d + 2 * Nn];
        float m0 = hi_f(v0), m1 = hi_f(v1), m2 = hi_f(v2);
        float x0 = lo_f(v0), x1 = lo_f(v1), x2 = lo_f(v2);
        const float* r1 = Wlv + (64 + j) * 32 + w0;
        const float* r2 = W101 + j * 32 + w0;
        #pragma unroll
        for (int w = 0; w < 16; ++w) {
            float wv = r1[w], wx = r2[w];
            hj[w][0] += m0 * wv + x0 * wx;
            hj[w][1] += m1 * wv + x1 * wx;
            hj[w][2] += m2 * wv + x2 * wx;
        }
    }

    #pragma unroll
    for (int w = 0; w < 16; ++w) {
        float g = gbuf[(w0 + w) * Nn + nc];
        #pragma unroll
        for (int c = 0; c < 3; ++c) {
            float hv = av[c] * ss[w] + a_s * hj[w][c];
            st[t][w * 3 + c] = g * hv;
        }
    }
    __syncthreads();
    // coalesced write: each node's 48 floats are contiguous (192B = 3 lines)
    int off = 64 + w0 * 3;
    for (int k = 0; k < 48; ++k) {
        int f = k * 256 + t;
        int node = f / 48;
        int idx = f - node * 48;
        int n2 = n0 + node;
        if (n2 < Nn) out[(size_t)n2 * DIM + off + idx] = st[node][idx];
    }
}

extern "C" void kernel_launch(void* const* d_in, const int* in_sizes, int n_in,
                              void* d_out, int out_size, void* d_ws, size_t ws_size,
                              hipStream_t stream) {
    const float* feats = (const float*)d_in[0];
    const float* attrs = (const float*)d_in[1];
    const float* em    = (const float*)d_in[2];
    const int*   ei    = (const int*)d_in[3];
    const float* w00   = (const float*)d_in[4];
    const float* w01   = (const float*)d_in[5];
    const float* w10   = (const float*)d_in[6];
    const float* w11   = (const float*)d_in[7];
    const float* Wls   = (const float*)d_in[8];
    const float* Wlv   = (const float*)d_in[9];
    const float* W000  = (const float*)d_in[10];
    const float* W110  = (const float*)d_in[11];
    const float* W011  = (const float*)d_in[12];
    const float* W101  = (const float*)d_in[13];

    char* ws = (char*)d_ws;
    int*   bucket = (int*)  (ws);                  // 19,200,000 B [N][48] int
    int*   cnt    = (int*)  (ws + 19200000);       //    400,000 B [N] int
    u32*   mfT    = (u32*)  (ws + 19600000);       // 64,000,000 B [160][N] u32 (msg|feat bf16)
    float* gbuf   = (float*)(ws + 83600000);       // 12,800,000 B [32][N] f32 gates
    float* W      = (float*)(ws + 96400000);       //     98,304 B weights

    hipMemsetAsync(cnt, 0, Nn * sizeof(int), stream);

    hist_fill_k<<<(Ee + 255) / 256, 256, 0, stream>>>(ei, cnt, bucket);

    gather_tr_k<<<(Nn + 63) / 64, 512, 0, stream>>>(em, feats, bucket, cnt, mfT);

    prep_weights_k<<<96, 256, 0, stream>>>(Wls, Wlv, W000, W110, W011, W101,
                                           w00, w01, w10, w11, W);

    node_s_k<<<dim3((Nn + 255) / 256, 3), 256, 0, stream>>>(mfT, attrs, W,
                                                            (float*)d_out, gbuf);

    node_v_k<<<dim3((Nn + 255) / 256, 2), 256, 0, stream>>>(mfT, attrs, W,
                                                            gbuf, (float*)d_out);
}

// Round 4
// 717.663 us; speedup vs baseline: 1.1162x; 1.0364x over previous
//
#include <hip/hip_runtime.h>

typedef unsigned short u16;
typedef unsigned int u32;

#define Nn 100000
#define Ee 500000
#define DIM 160
#define CAP 48

__device__ __forceinline__ u16 f2bf(float f) {
    u32 i = __float_as_uint(f);
    return (u16)((i + 0x7FFFu + ((i >> 16) & 1u)) >> 16);
}

__device__ __forceinline__ u32 eclamp(int v) {
    u32 e = (u32)v;
    return (e > (u32)(Ee - 1)) ? (u32)(Ee - 1) : e;   // garbage-safe
}

// ---------------- K1: histogram + bucket fill (one pass) ---------------------
__global__ __launch_bounds__(256) void hist_fill_k(const int* __restrict__ ei,
                                                   int* __restrict__ cnt,
                                                   int* __restrict__ bucket) {
    int e = blockIdx.x * 256 + threadIdx.x;
    if (e >= Ee) return;
    int dst = ei[Ee + e];                 // edge_index row 1 (dst)
    int pos = atomicAdd(&cnt[dst], 1);
    if (pos < CAP) bucket[(size_t)dst * CAP + pos] = e;
}

// ------- K2: fused gather + /sqrt5 + feats + bf16-pack + transpose -----------
// Block = 512 threads (8 waves), 64 nodes; wave per node (8 sequential).
// Latency fix: next node's cnt/bucket/feats loads are issued blindly (clamped
// edge ids + zero-masked FMA) before the current node's accumulate waits, and
// all row loads of a node issue in ONE round (tiered 4 / 8 edges, wave-uniform
// branch). Rare deg>8 handled by a masked int4 tail loop.
__global__ __launch_bounds__(512) void gather_tr_k(const float* __restrict__ em,
                                                   const float* __restrict__ feats,
                                                   const int* __restrict__ bucket,
                                                   const int* __restrict__ cnt,
                                                   u32* __restrict__ mfT) {
    __shared__ u32 tile[160][65];         // stride 65 % 32 == 1: conflict-free
    int n0 = blockIdx.x * 64;
    int w = threadIdx.x >> 6;             // wave id 0..7
    int lane = threadIdx.x & 63;
    int l32 = lane & 31;
    const float s = 0.4472135954999579f;  // 1/sqrt(5)

    // ---- prologue: prefetch node i=0 ----
    int nfirst = n0 + w * 8;
    int npc = (nfirst < Nn) ? nfirst : (Nn - 1);
    int degC = cnt[npc];
    const int* bC = bucket + (size_t)npc * CAP;
    int4 eeA = *reinterpret_cast<const int4*>(bC);
    int4 eeB = *reinterpret_cast<const int4*>(bC + 4);
    const float* fC = feats + (size_t)npc * DIM;
    float fc0 = fC[lane], fc1 = fC[64 + lane], fc2 = fC[128 + l32];

    for (int i = 0; i < 8; ++i) {
        int col = w * 8 + i;
        int n = n0 + col;
        bool act = (n < Nn);
        int deg = act ? degC : 0;
        if (deg > CAP) deg = CAP;
        int4 curA = eeA, curB = eeB;
        float g0 = act ? fc0 : 0.f;
        float g1 = act ? fc1 : 0.f;
        float g2 = act ? fc2 : 0.f;

        // ---- prefetch node i+1 (independent of everything below) ----
        if (i < 7) {
            int n2 = n + 1;
            int n2c = (n2 < Nn) ? n2 : (Nn - 1);
            degC = cnt[n2c];
            const int* bN = bucket + (size_t)n2c * CAP;
            eeA = *reinterpret_cast<const int4*>(bN);
            eeB = *reinterpret_cast<const int4*>(bN + 4);
            const float* fN = feats + (size_t)n2c * DIM;
            fc0 = fN[lane]; fc1 = fN[64 + lane]; fc2 = fN[128 + l32];
        }

        float a0 = 0.f, a1 = 0.f, a2 = 0.f;
        if (deg > 0) {
            u32 e0 = eclamp(curA.x), e1 = eclamp(curA.y);
            u32 e2 = eclamp(curA.z), e3 = eclamp(curA.w);
            float m0 = 1.f;                       // deg >= 1
            float m1 = (1 < deg) ? 1.f : 0.f;
            float m2 = (2 < deg) ? 1.f : 0.f;
            float m3 = (3 < deg) ? 1.f : 0.f;
            const float* p0 = em + (size_t)e0 * DIM;
            const float* p1 = em + (size_t)e1 * DIM;
            const float* p2 = em + (size_t)e2 * DIM;
            const float* p3 = em + (size_t)e3 * DIM;
            if (deg <= 4) {                       // wave-uniform tier branch
                float t00 = p0[lane],      t10 = p1[lane],      t20 = p2[lane],      t30 = p3[lane];
                float t01 = p0[64 + lane], t11 = p1[64 + lane], t21 = p2[64 + lane], t31 = p3[64 + lane];
                float t02 = p0[128 + l32], t12 = p1[128 + l32], t22 = p2[128 + l32], t32 = p3[128 + l32];
                a0 = m0 * t00 + m1 * t10 + m2 * t20 + m3 * t30;
                a1 = m0 * t01 + m1 * t11 + m2 * t21 + m3 * t31;
                a2 = m0 * t02 + m1 * t12 + m2 * t22 + m3 * t32;
            } else {
                u32 e4 = eclamp(curB.x), e5 = eclamp(curB.y);
                u32 e6 = eclamp(curB.z), e7 = eclamp(curB.w);
                float m4 = 1.f;                   // deg >= 5
                float m5 = (5 < deg) ? 1.f : 0.f;
                float m6 = (6 < deg) ? 1.f : 0.f;
                float m7 = (7 < deg) ? 1.f : 0.f;
                const float* p4 = em + (size_t)e4 * DIM;
                const float* p5 = em + (size_t)e5 * DIM;
                const float* p6 = em + (size_t)e6 * DIM;
                const float* p7 = em + (size_t)e7 * DIM;
                float t00 = p0[lane],      t10 = p1[lane],      t20 = p2[lane],      t30 = p3[lane];
                float t40 = p4[lane],      t50 = p5[lane],      t60 = p6[lane],      t70 = p7[lane];
                float t01 = p0[64 + lane], t11 = p1[64 + lane], t21 = p2[64 + lane], t31 = p3[64 + lane];
                float t41 = p4[64 + lane], t51 = p5[64 + lane], t61 = p6[64 + lane], t71 = p7[64 + lane];
                float t02 = p0[128 + l32], t12 = p1[128 + l32], t22 = p2[128 + l32], t32 = p3[128 + l32];
                float t42 = p4[128 + l32], t52 = p5[128 + l32], t62 = p6[128 + l32], t72 = p7[128 + l32];
                a0 = (m0 * t00 + m1 * t10 + m2 * t20 + m3 * t30)
                   + (m4 * t40 + m5 * t50 + m6 * t60 + m7 * t70);
                a1 = (m0 * t01 + m1 * t11 + m2 * t21 + m3 * t31)
                   + (m4 * t41 + m5 * t51 + m6 * t61 + m7 * t71);
                a2 = (m0 * t02 + m1 * t12 + m2 * t22 + m3 * t32)
                   + (m4 * t42 + m5 * t52 + m6 * t62 + m7 * t72);
                // ---- rare deep tail (deg > 8, ~7% of nodes) ----
                if (deg > 8) {
                    const int* bt = bucket + (size_t)n * CAP;
                    for (int k = 8; k < deg; k += 4) {
                        int4 ee = *reinterpret_cast<const int4*>(bt + k);
                        u32 q0 = eclamp(ee.x), q1 = eclamp(ee.y);
                        u32 q2 = eclamp(ee.z), q3 = eclamp(ee.w);
                        float u0 = 1.f;           // k < deg
                        float u1 = (k + 1 < deg) ? 1.f : 0.f;
                        float u2 = (k + 2 < deg) ? 1.f : 0.f;
                        float u3 = (k + 3 < deg) ? 1.f : 0.f;
                        const float* q0p = em + (size_t)q0 * DIM;
                        const float* q1p = em + (size_t)q1 * DIM;
                        const float* q2p = em + (size_t)q2 * DIM;
                        const float* q3p = em + (size_t)q3 * DIM;
                        a0 += u0 * q0p[lane] + u1 * q1p[lane]
                            + u2 * q2p[lane] + u3 * q3p[lane];
                        a1 += u0 * q0p[64 + lane] + u1 * q1p[64 + lane]
                            + u2 * q2p[64 + lane] + u3 * q3p[64 + lane];
                        a2 += u0 * q0p[128 + l32] + u1 * q1p[128 + l32]
                            + u2 * q2p[128 + l32] + u3 * q3p[128 + l32];
                    }
                }
            }
        }

        tile[lane][col]      = ((u32)f2bf(a0 * s) << 16) | f2bf(g0);
        tile[64 + lane][col] = ((u32)f2bf(a1 * s) << 16) | f2bf(g1);
        if (lane < 32)
            tile[128 + lane][col] = ((u32)f2bf(a2 * s) << 16) | f2bf(g2);
    }
    __syncthreads();
    int n = n0 + lane;
    if (n < Nn) {
        for (int k = 0; k < 20; ++k) {        // 160 rows / 8 waves
            int d = w * 20 + k;
            mfT[d * Nn + n] = tile[d][lane];  // 256B contiguous per wave
        }
    }
}

// ---------------- K4: pre-scale + fuse all weight factors (f32) --------------
// Layout in W (f32): Wls' [96][96] @0, Wlv' [96][32] @9216, W000' [64][96] @12288,
//                    W110' [32][96] @18432, W011' [64][32] @21504, W101' [32][32] @23552
__global__ __launch_bounds__(256) void prep_weights_k(
    const float* __restrict__ Wls, const float* __restrict__ Wlv,
    const float* __restrict__ W000, const float* __restrict__ W110,
    const float* __restrict__ W011, const float* __restrict__ W101,
    const float* __restrict__ w00, const float* __restrict__ w01,
    const float* __restrict__ w10, const float* __restrict__ w11,
    float* __restrict__ W) {
    int i = blockIdx.x * 256 + threadIdx.x;
    const float inv_fan = 0.10206207261596577f;  // 1/sqrt(96)
    const float IS3 = 0.5773502691896258f;
    if (i < 9216) {
        int u = i / 96;
        float sc = inv_fan * (u < 64 ? w00[u] : IS3 * w11[u - 64]);
        W[i] = Wls[i] * sc;
    } else if (i < 12288) {
        int j = i - 9216; int u = j / 32;
        float sc = inv_fan * (u < 64 ? w01[u] : w10[u - 64]);
        W[i] = Wlv[j] * sc;
    } else if (i < 18432) {
        W[i] = W000[i - 12288] * 0.08838834764831845f;   // inv2/sqrt(64)
    } else if (i < 21504) {
        W[i] = W110[i - 18432] * (0.125f * IS3);         // inv2/sqrt(32) * IS3
    } else if (i < 23552) {
        W[i] = W011[i - 21504] * 0.08838834764831845f;   // inv2/sqrt(64)
    } else {
        W[i] = W101[i - 23552] * 0.125f;                 // inv2/sqrt(32)
    }
}

__device__ __forceinline__ float hi_f(u32 v) { return __uint_as_float(v & 0xFFFF0000u); }  // msg
__device__ __forceinline__ float lo_f(u32 v) { return __uint_as_float(v << 16); }          // feat

// ---------------- K5: h_s — one thread per (node, wb) ------------------------
// grid (391, 3): wb = blockIdx.y selects 32-wide w-block of the 96 h_s cols.
// wb 0,1 -> silu -> out[:, 0:64]; wb 2 -> sigmoid gates -> gbuf [32][N].
__global__ __launch_bounds__(256) void node_s_k(
    const u32* __restrict__ mfT, const float* __restrict__ attrs,
    const float* __restrict__ W, float* __restrict__ out,
    float* __restrict__ gbuf) {
    __shared__ float st[256][33];
    int wb = blockIdx.y;
    int n0 = blockIdx.x * 256;
    int t = threadIdx.x;
    int n = n0 + t;
    bool active = (n < Nn);
    int nc = active ? n : (Nn - 1);

    const float* Wls  = W;
    const float* W000 = W + 12288;
    const float* W110 = W + 18432;

    float4 a = *reinterpret_cast<const float4*>(attrs + (size_t)nc * 4);
    float a_s = a.x, av0 = a.y, av1 = a.z, av2 = a.w;

    float accU[32], accJ[32];
    #pragma unroll
    for (int w = 0; w < 32; ++w) { accU[w] = 0.f; accJ[w] = 0.f; }

    const float* R1 = Wls + wb * 32;     // row stride 96
    const float* R2 = W000 + wb * 32;
    const float* R3 = W110 + wb * 32;

    // s-part: both terms scale by a_s -> factored out of the loop
    for (int u = 0; u < 64; ++u) {
        u32 v = mfT[u * Nn + nc];
        float m = hi_f(v);
        float x = lo_f(v);
        const float* r1 = R1 + u * 96;
        const float* r2 = R2 + u * 96;
        #pragma unroll
        for (int w = 0; w < 32; ++w) accU[w] += m * r1[w] + x * r2[w];
    }
    // v-dot part (not scaled by a_s)
    for (int j = 0; j < 32; ++j) {
        int d = (64 + 3 * j) * Nn + nc;
        u32 v0 = mfT[d], v1 = mfT[d + Nn], v2 = mfT[d + 2 * Nn];
        float dv = hi_f(v0) * av0 + hi_f(v1) * av1 + hi_f(v2) * av2;
        float dx = lo_f(v0) * av0 + lo_f(v1) * av1 + lo_f(v2) * av2;
        const float* r1 = R1 + (64 + j) * 96;
        const float* r2 = R3 + j * 96;
        #pragma unroll
        for (int w = 0; w < 32; ++w) accJ[w] += dv * r1[w] + dx * r2[w];
    }

    if (wb < 2) {
        #pragma unroll
        for (int w = 0; w < 32; ++w) {
            float h = a_s * accU[w] + accJ[w];
            st[t][w] = h / (1.f + __expf(-h));   // silu
        }
        __syncthreads();
        // coalesced write: 8192 floats, lane-contiguous, full 64B lines
        int off = wb * 32;
        for (int k = 0; k < 32; ++k) {
            int f = k * 256 + t;
            int node = f >> 5, w = f & 31;
            int n2 = n0 + node;
            if (n2 < Nn) out[(size_t)n2 * DIM + off + w] = st[node][w];
        }
    } else {
        #pragma unroll
        for (int w = 0; w < 32; ++w) {
            float h = a_s * accU[w] + accJ[w];
            if (active) gbuf[w * Nn + n] = 1.f / (1.f + __expf(-h));
        }
    }
}

// ---------------- K6: h_v — one thread per (node, half) ----------------------
// grid (391, 2): half = blockIdx.y selects 16 of the 32 v-channels; all 3
// components per thread so each node's 48 output floats are contiguous.
__global__ __launch_bounds__(256) void node_v_k(
    const u32* __restrict__ mfT, const float* __restrict__ attrs,
    const float* __restrict__ W, const float* __restrict__ gbuf,
    float* __restrict__ out) {
    __shared__ float st[256][49];
    int half = blockIdx.y;
    int w0 = half * 16;
    int n0 = blockIdx.x * 256;
    int t = threadIdx.x;
    int n = n0 + t;
    bool active = (n < Nn);
    int nc = active ? n : (Nn - 1);

    const float* Wlv  = W + 9216;   // [96][32]
    const float* W011 = W + 21504;  // [64][32]
    const float* W101 = W + 23552;  // [32][32]

    float4 a = *reinterpret_cast<const float4*>(attrs + (size_t)nc * 4);
    float a_s = a.x;
    float av[3] = {a.y, a.z, a.w};

    // ss[w] = sum_u ms[u]*Wlv'[u][w] + xs[u]*W011'[u][w]
    float ss[16];
    #pragma unroll
    for (int w = 0; w < 16; ++w) ss[w] = 0.f;
    for (int u = 0; u < 64; ++u) {
        u32 v = mfT[u * Nn + nc];
        float m = hi_f(v);
        float x = lo_f(v);
        const float* r1 = Wlv + u * 32 + w0;
        const float* r2 = W011 + u * 32 + w0;
        #pragma unroll
        for (int w = 0; w < 16; ++w) ss[w] += m * r1[w] + x * r2[w];
    }

    // hj[w][c] = sum_j mv[j][c]*Wlv'[64+j][w] + xv[j][c]*W101'[j][w]  (x a_s later)
    float hj[16][3];
    #pragma unroll
    for (int w = 0; w < 16; ++w) {
        hj[w][0] = 0.f; hj[w][1] = 0.f; hj[w][2] = 0.f;
    }
    for (int j = 0; j < 32; ++j) {
        int d = (64 + 3 * j) * Nn + nc;
        u32 v0 = mfT[d], v1 = mfT[d + Nn], v2 = mfT[d + 2 * Nn];
        float m0 = hi_f(v0), m1 = hi_f(v1), m2 = hi_f(v2);
        float x0 = lo_f(v0), x1 = lo_f(v1), x2 = lo_f(v2);
        const float* r1 = Wlv + (64 + j) * 32 + w0;
        const float* r2 = W101 + j * 32 + w0;
        #pragma unroll
        for (int w = 0; w < 16; ++w) {
            float wv = r1[w], wx = r2[w];
            hj[w][0] += m0 * wv + x0 * wx;
            hj[w][1] += m1 * wv + x1 * wx;
            hj[w][2] += m2 * wv + x2 * wx;
        }
    }

    #pragma unroll
    for (int w = 0; w < 16; ++w) {
        float g = gbuf[(w0 + w) * Nn + nc];
        #pragma unroll
        for (int c = 0; c < 3; ++c) {
            float hv = av[c] * ss[w] + a_s * hj[w][c];
            st[t][w * 3 + c] = g * hv;
        }
    }
    __syncthreads();
    // coalesced write: each node's 48 floats are contiguous (192B = 3 lines)
    int off = 64 + w0 * 3;
    for (int k = 0; k < 48; ++k) {
        int f = k * 256 + t;
        int node = f / 48;
        int idx = f - node * 48;
        int n2 = n0 + node;
        if (n2 < Nn) out[(size_t)n2 * DIM + off + idx] = st[node][idx];
    }
}

extern "C" void kernel_launch(void* const* d_in, const int* in_sizes, int n_in,
                              void* d_out, int out_size, void* d_ws, size_t ws_size,
                              hipStream_t stream) {
    const float* feats = (const float*)d_in[0];
    const float* attrs = (const float*)d_in[1];
    const float* em    = (const float*)d_in[2];
    const int*   ei    = (const int*)d_in[3];
    const float* w00   = (const float*)d_in[4];
    const float* w01   = (const float*)d_in[5];
    const float* w10   = (const float*)d_in[6];
    const float* w11   = (const float*)d_in[7];
    const float* Wls   = (const float*)d_in[8];
    const float* Wlv   = (const float*)d_in[9];
    const float* W000  = (const float*)d_in[10];
    const float* W110  = (const float*)d_in[11];
    const float* W011  = (const float*)d_in[12];
    const float* W101  = (const float*)d_in[13];

    char* ws = (char*)d_ws;
    int*   bucket = (int*)  (ws);                  // 19,200,000 B [N][48] int
    int*   cnt    = (int*)  (ws + 19200000);       //    400,000 B [N] int
    u32*   mfT    = (u32*)  (ws + 19600000);       // 64,000,000 B [160][N] u32 (msg|feat bf16)
    float* gbuf   = (float*)(ws + 83600000);       // 12,800,000 B [32][N] f32 gates
    float* W      = (float*)(ws + 96400000);       //     98,304 B weights

    hipMemsetAsync(cnt, 0, Nn * sizeof(int), stream);

    hist_fill_k<<<(Ee + 255) / 256, 256, 0, stream>>>(ei, cnt, bucket);

    gather_tr_k<<<(Nn + 63) / 64, 512, 0, stream>>>(em, feats, bucket, cnt, mfT);

    prep_weights_k<<<96, 256, 0, stream>>>(Wls, Wlv, W000, W110, W011, W101,
                                           w00, w01, w10, w11, W);

    node_s_k<<<dim3((Nn + 255) / 256, 3), 256, 0, stream>>>(mfT, attrs, W,
                                                            (float*)d_out, gbuf);

    node_v_k<<<dim3((Nn + 255) / 256, 2), 256, 0, stream>>>(mfT, attrs, W,
                                                            gbuf, (float*)d_out);
}